// Round 9
// baseline (270.404 us; speedup 1.0000x reference)
//
#include <hip/hip_runtime.h>
#include <math.h>

// Problem constants
#define B_   64
#define T_   256
#define W_   20
#define NP_  6
#define NT_  12
#define CC_  32      // CONV_CH
#define FD_  8       // FRAG_DIM
#define PR_  64      // PROJ

#define LOG2E  1.4426950408889634f

typedef float v2f __attribute__((ext_vector_type(2)));
typedef _Float16 half2_t __attribute__((ext_vector_type(2)));

// Pin a single 32-bit value into a VGPR (opaque def; blocks remat/spill-sink).
#define PINU(x) asm volatile("" : "+v"(x))
// Wave-local LDS ordering: drain LDS ops only; no vmcnt, no barrier.
#define WAVE_SYNC() asm volatile("s_waitcnt lgkmcnt(0)" ::: "memory")

#define H2(u) __builtin_bit_cast(half2_t, (u))
// Native base-2 exp: exactly v_exp_f32. R3 POST-MORTEM: libm exp2f() goes
// through the OCML correctly-rounded path (multi-inst fixup) without
// fast-math -> +30us on the 256-step serial chain. Never use libm exp/exp2
// on the LSTM critical path.
#define EXP2N(x) __builtin_amdgcn_exp2f(x)

// ============================ SESSION LEDGER =============================
// Best verified build: R4 config @ 196.0us (encoder ~78, lstm 106, head ~8)
// R8 re-verified: 196.1us, spill-clean.
// Falsified levers (do not retry):
//  - encoder (256,5) or >=48 extra pinned VGPRs: scratch spill. Spill signal
//    is FETCH/WRITE ballooning, NOT VGPR_Count (can still read 64).
//  - encoder barrier removal via per-wave redundant w2p staging: +33us.
//  - lstm chain restructuring: per-step ~1000cy invariant (~106us).
//  - lstm 2-wave K-split: +9us (barrier drains vmcnt; exchange > saving).
// R9 (this round): lstm VALUBusy ~16% on busy CUs -> 84% latency-stalled.
// Interleave TWO independent batch recurrences per wave (Whh regs shared,
// zero communication) to hide latency with intra-wave TLP.
// =========================================================================

__device__ __forceinline__ unsigned packh2(float a, float b) {
    union { _Float16 h[2]; unsigned u; } cv;
    cv.h[0] = (_Float16)a; cv.h[1] = (_Float16)b;
    return cv.u;
}

// Fast activations: v_rcp_f32 instead of IEEE division.
__device__ __forceinline__ float sigmoidf_(float x) {
    return __builtin_amdgcn_rcpf(1.0f + EXP2N(-LOG2E * x));  // exact at +-inf
}

// -------------------------------------------------------------------------
// Packed-weight sections (32-bit words), aliased into the hout workspace
// region: they are consumed by encoder_kernel and dead before lstm_kernel
// starts writing hout (stream order guarantees no overlap in time).
// -------------------------------------------------------------------------
#define W1PT_N  (18 * 64)          // conv1 wts, f16-pair, [m*3+k][lane]
#define W2G_N   (64 * 48)          // conv2 wts, f16-pair, [row][m*3+k]
#define PRWT_N  (18 * 64 * 4)      // proj wts, f32, float4 idx [kq][lane]
#define WIHT_N  (16 * 4 * 64 * 4)  // Wih, f32, float4 idx [kq][gate][lane]
#define BSUM_N  256                // bih + bhh
#define PREP_TOTAL (W1PT_N + W2G_N + PRWT_N + WIHT_N + BSUM_N)  // 25472

// -------------------------------------------------------------------------
// Kernel 0: weight repack (coalesced encoder weight loads; R11 win).
// -------------------------------------------------------------------------
__global__ void prep_kernel(
    const float* __restrict__ pw1, const float* __restrict__ tw1,
    const float* __restrict__ pw2, const float* __restrict__ tw2,
    const float* __restrict__ prw, const float* __restrict__ Wih,
    const float* __restrict__ bih, const float* __restrict__ bhh,
    unsigned* __restrict__ w1pT, unsigned* __restrict__ w2g,
    float* __restrict__ prwT4, float* __restrict__ wihT4,
    float* __restrict__ bsum)
{
    int id = blockIdx.x * 256 + threadIdx.x;
    if (id < W1PT_N) {
        // w1pT[m3*64 + lane] = packed conv1 pair (zero-padded for pressure m>=3)
        int lane = id & 63, m3 = id >> 6;
        int s = lane >> 5, o = lane & 31;
        int m = m3 / 3, k = m3 - 3 * m;
        unsigned v;
        if (s == 0)
            v = (m < 3) ? packh2(pw1[o * 18 + (2 * m) * 3 + k],
                                 pw1[o * 18 + (2 * m + 1) * 3 + k]) : 0u;
        else
            v = packh2(tw1[o * 36 + (2 * m) * 3 + k],
                       tw1[o * 36 + (2 * m + 1) * 3 + k]);
        w1pT[id] = v;
        return;
    }
    id -= W1PT_N;
    if (id < W2G_N) {
        // w2g[r*48 + c]: packed conv2 pair for out-row r (p:0-31, t:32-63)
        int r = id / 48, c = id - 48 * r;
        int s = r >> 5, o = r & 31;
        int m = c / 3, k = c - 3 * m;
        const float* src = s ? tw2 : pw2;
        w2g[id] = packh2(src[o * 96 + (2 * m) * 3 + k],
                         src[o * 96 + (2 * m + 1) * 3 + k]);
        return;
    }
    id -= W2G_N;
    if (id < PRWT_N) {
        // float4 index (kq*64 + lane), element j: prw[lane][kq*4+j]
        int j = id & 3, t = id >> 2;
        int lane = t & 63, kq = t >> 6;
        prwT4[id] = prw[lane * 72 + kq * 4 + j];
        return;
    }
    id -= PRWT_N;
    if (id < WIHT_N) {
        // float4 index ((kq*4+gi)*64 + lane), element j: Wih[gi*64+lane][kq*4+j]
        int j = id & 3, t = id >> 2;
        int lane = t & 63, gg = t >> 6;
        int gi = gg & 3, kq = gg >> 2;
        wihT4[id] = Wih[(gi * 64 + lane) * 64 + kq * 4 + j];
        return;
    }
    id -= WIHT_N;
    if (id < BSUM_N) bsum[id] = bih[id] + bhh[id];
}

// -------------------------------------------------------------------------
// Kernel 1: encoders + projection + LSTM input-gate precompute.
// R4-EXACT structure (verified ~78us, FETCH 12MB, WRITE 16MB, VGPR 64):
// cooperative w2p staging + the ONE __syncthreads + (256,4). See ledger.
// -------------------------------------------------------------------------
__global__ __launch_bounds__(256, 4) void encoder_kernel(
    const float* __restrict__ pressure, const float* __restrict__ torque,
    const float* __restrict__ frag,
    const float* __restrict__ pb1, const float* __restrict__ tb1,
    const float* __restrict__ pb2, const float* __restrict__ tb2,
    const float* __restrict__ fw,  const float* __restrict__ fb,
    const float* __restrict__ prb,
    const unsigned* __restrict__ w1pT, const unsigned* __restrict__ w2g,
    const float* __restrict__ prwT4, const float* __restrict__ wihT4,
    const float* __restrict__ bsum,
    float* __restrict__ xg)             // (B,T,4gates,64units) gate-blocked
{
    const int tid  = threadIdx.x;       // 0..255
    const int wv   = tid >> 6;          // wave 0..3
    const int lane = tid & 63;
    const int bt   = blockIdx.x * 4 + wv;   // window id
    const int b    = bt >> 8;
    const int  o   = lane & 31;
    const bool isp = lane < 32;
    const int  s   = isp ? 0 : 1;       // stream: 0=pressure, 1=torque

    __shared__ unsigned w2p[64 * 49];                    // 12544 B packed conv2 wts
    __shared__ __align__(16) unsigned xwp[4][2][120];    //  3840 B [wave][stream][pair*20+pos]
    __shared__ __align__(16) unsigned h1p[4][2][320];    // 10240 B
    __shared__ __align__(16) float catb4[4][72];
    __shared__ __align__(16) float featsh4[4][64];

    float* catb   = catb4[wv];
    float* featsh = featsh4[wv];

    // ---- stage conv2 weights once per block (coalesced b32 from w2g) ----
    for (int idx = tid; idx < 64 * 48; idx += 256) {
        int r = idx / 48, c = idx - r * 48;
        w2p[r * 49 + c] = w2g[idx];
    }

    // ---- zero + stage own window as packed f16 pairs (transposed) ----
    {
        unsigned* xz = &xwp[wv][0][0];
        #pragma unroll
        for (int idx = lane; idx < 240; idx += 64) xz[idx] = 0;   // pads pressure rows 3..5
    }
    const float* pin = pressure + (size_t)bt * (W_ * NP_);
    for (int idx = lane; idx < W_ * NP_; idx += 64) {
        int w = idx / NP_, i = idx - w * NP_;
        ((_Float16*)&xwp[wv][0][(i >> 1) * 20 + w])[i & 1] = (_Float16)pin[idx];
    }
    const float* tin = torque + (size_t)bt * (W_ * NT_);
    for (int idx = lane; idx < W_ * NT_; idx += 64) {
        int w = idx / NT_, i = idx - w * NT_;
        ((_Float16*)&xwp[wv][1][(i >> 1) * 20 + w])[i & 1] = (_Float16)tin[idx];
    }
    if (lane < FD_) catb[64 + lane] = fmaxf(frag[b] * fw[lane] + fb[lane], 0.0f);

    // ---- conv1 weights: one coalesced b32 load per pair slot ----
    unsigned w1p[18];
    #pragma unroll
    for (int m3 = 0; m3 < 18; ++m3) w1p[m3] = w1pT[m3 * 64 + lane];

    const float bz1 = isp ? pb1[o] : tb1[o];
    const float bz2 = isp ? pb2[o] : tb2[o];
    WAVE_SYNC();    // xwp visible within the wave

    // ---- conv1: 6 pair-rows x 3 taps x 18 pos, dot2 f16 -> f32 acc ----
    {
        const unsigned* xr = &xwp[wv][s][0];
        float acc[18];
        #pragma unroll
        for (int l = 0; l < 18; ++l) acc[l] = bz1;
        #pragma unroll
        for (int m = 0; m < 6; ++m) {
            uint4 r4[5];
            const uint4* rp = (const uint4*)(xr + m * 20);
            #pragma unroll
            for (int q = 0; q < 5; ++q) r4[q] = rp[q];        // broadcast b128
            const unsigned* rw = (const unsigned*)r4;
            const half2_t wk0 = H2(w1p[m * 3]), wk1 = H2(w1p[m * 3 + 1]), wk2 = H2(w1p[m * 3 + 2]);
            #pragma unroll
            for (int l = 0; l < 18; ++l) {
                float a = acc[l];
                a = __builtin_amdgcn_fdot2(wk0, H2(rw[l]),     a, false);
                a = __builtin_amdgcn_fdot2(wk1, H2(rw[l + 1]), a, false);
                a = __builtin_amdgcn_fdot2(wk2, H2(rw[l + 2]), a, false);
                acc[l] = a;
            }
        }
        #pragma unroll
        for (int l = 0; l < 18; ++l)
            ((_Float16*)&h1p[wv][s][(o >> 1) * 20 + l])[o & 1] = (_Float16)fmaxf(acc[l], 0.0f);
    }
    __syncthreads();   // the ONE real barrier: w2p (cross-wave) + h1p ready

    // ---- conv2: 16 pair-rows x 3 taps x 16 pos, weights from LDS ----
    {
        const unsigned* hr   = &h1p[wv][s][0];
        const unsigned* wrow = w2p + lane * 49;   // row stride 49: conflict-free
        float sacc[16];
        #pragma unroll
        for (int l = 0; l < 16; ++l) sacc[l] = bz2;
        #pragma unroll 4
        for (int m = 0; m < 16; ++m) {
            uint4 r4[5];
            const uint4* rp = (const uint4*)(hr + m * 20);
            #pragma unroll
            for (int q = 0; q < 5; ++q) r4[q] = rp[q];        // broadcast b128
            const unsigned* rw = (const unsigned*)r4;
            const half2_t wk0 = H2(wrow[m * 3]), wk1 = H2(wrow[m * 3 + 1]), wk2 = H2(wrow[m * 3 + 2]);
            #pragma unroll
            for (int l = 0; l < 16; ++l) {
                float a = sacc[l];
                a = __builtin_amdgcn_fdot2(wk0, H2(rw[l]),     a, false);
                a = __builtin_amdgcn_fdot2(wk1, H2(rw[l + 1]), a, false);
                a = __builtin_amdgcn_fdot2(wk2, H2(rw[l + 2]), a, false);
                sacc[l] = a;
            }
        }
        float m2 = 0.0f;
        #pragma unroll
        for (int l = 0; l < 16; ++l) m2 += fmaxf(sacc[l], 0.0f);
        catb[lane] = m2 * 0.0625f;               // pf -> [0..31], tf -> [32..63]
    }
    WAVE_SYNC();    // catb visible within the wave

    // ---- projection 72 -> 64, relu (f32, coalesced lane-interleaved wts) ----
    {
        float acc = prb[lane];
        const float4* w4 = (const float4*)prwT4;   // [q*64 + lane]
        const float4* c4 = (const float4*)catb;
        #pragma unroll
        for (int q = 0; q < 18; ++q) {
            float4 w = w4[q * 64 + lane];
            float4 cv = c4[q];
            acc += w.x * cv.x + w.y * cv.y + w.z * cv.z + w.w * cv.w;
        }
        featsh[lane] = fmaxf(acc, 0.0f);
    }
    WAVE_SYNC();    // featsh visible within the wave

    // ---- xg = feat @ Wih.T + bsum ; coalesced wts + coalesced stores ----
    {
        float4 fr[16];
        const float4* f4 = (const float4*)featsh;
        #pragma unroll
        for (int q = 0; q < 16; ++q) fr[q] = f4[q];
        float* xgrow = xg + (size_t)bt * 256;
        const float4* w44 = (const float4*)wihT4;  // [(q*4+gi)*64 + lane]
        #pragma unroll
        for (int gi = 0; gi < 4; ++gi) {
            float acc = bsum[gi * 64 + lane];
            #pragma unroll
            for (int q = 0; q < 16; ++q) {
                float4 w = w44[(q * 4 + gi) * 64 + lane];
                acc += w.x * fr[q].x + w.y * fr[q].y + w.z * fr[q].z + w.w * fr[q].w;
            }
            xgrow[gi * 64 + lane] = acc;         // 256B contiguous per store inst
        }
    }
}

// -------------------------------------------------------------------------
// Kernel 2: LSTM — R9: TWO independent batch recurrences per wave.
// Wave is latency-stalled 84% of the time (VALUBusy ~16% on busy CUs);
// batches share Whh so the 128 weight VGPRs serve both. 16 dot chains +
// 2 activation chains interleave: chain B issues while chain A waits.
// Per-element numerics identical to R4 (same partial-acc order, same ops).
// Zero communication, zero barriers; in-order wave-local LDS h roundtrip
// (R4-proven). grid = B/2 = 32 blocks.
// -------------------------------------------------------------------------
__global__ __launch_bounds__(64, 1) void lstm_kernel(
    const float* __restrict__ xg,     // (B,T,4,64), bias already included
    const float* __restrict__ Whh,    // (256,64)
    float* __restrict__ hout,         // (B, T/4, 64units, 4t)
    float* __restrict__ dout)         // full output buffer
{
    const int b0 = blockIdx.x;        // 0..31
    const int b1 = blockIdx.x + 32;   // 32..63
    const int j  = threadIdx.x;       // hidden unit index

    __shared__ __align__(16) _Float16 hs[2][64];   // h state per batch (256 B)

    // 4 Whh rows for unit j (i,f,g,o) as f16 pairs: 4 x 32 uints, pinned.
    // SHARED by both batch elements.
    unsigned wi[32], wf[32], wg[32], wo[32];
    {
        const v2f* ri = (const v2f*)(Whh + (size_t)(j)       * 64);
        const v2f* rf = (const v2f*)(Whh + (size_t)(64  + j) * 64);
        const v2f* rg = (const v2f*)(Whh + (size_t)(128 + j) * 64);
        const v2f* ro = (const v2f*)(Whh + (size_t)(192 + j) * 64);
        #pragma unroll
        for (int q = 0; q < 32; ++q) {
            v2f w;
            w = ri[q]; wi[q] = packh2(w.x, w.y);
            w = rf[q]; wf[q] = packh2(w.x, w.y);
            w = rg[q]; wg[q] = packh2(w.x, w.y);
            w = ro[q]; wo[q] = packh2(w.x, w.y);
        }
        #pragma unroll
        for (int q = 0; q < 32; ++q) { PINU(wi[q]); PINU(wf[q]); PINU(wg[q]); PINU(wo[q]); }
    }

    const float* xp0 = xg + (size_t)b0 * T_ * 256 + j;
    const float* xp1 = xg + (size_t)b1 * T_ * 256 + j;
    float4* hq40 = (float4*)(hout + (size_t)b0 * T_ * 64);
    float4* hq41 = (float4*)(hout + (size_t)b1 * T_ * 64);

    float c0 = 0.0f, h0 = 0.0f, c1 = 0.0f, h1 = 0.0f;
    hs[0][j] = (_Float16)0.0f;
    hs[1][j] = (_Float16)0.0f;
    WAVE_SYNC();    // once, before the loop

    // 2-deep prefetch of the 4 per-step gate scalars, both batches
    float p0c0 = xp0[0],   p0c1 = xp0[64],  p0c2 = xp0[128], p0c3 = xp0[192];
    float p0n0 = xp0[256], p0n1 = xp0[320], p0n2 = xp0[384], p0n3 = xp0[448];
    float p1c0 = xp1[0],   p1c1 = xp1[64],  p1c2 = xp1[128], p1c3 = xp1[192];
    float p1n0 = xp1[256], p1n1 = xp1[320], p1n2 = xp1[384], p1n3 = xp1[448];

    for (int tq = 0; tq < T_ / 4; ++tq) {
        float4 hacc0, hacc1;
        #pragma unroll
        for (int k = 0; k < 4; ++k) {
            const int t = tq * 4 + k;
            const int tp = (t + 2) * 256;   // unclamped: overflow lands in the
                                            // packed-weight/hout region (allocated,
                                            // never consumed)
            float f00 = xp0[tp], f01 = xp0[tp + 64], f02 = xp0[tp + 128], f03 = xp0[tp + 192];
            float f10 = xp1[tp], f11 = xp1[tp + 64], f12 = xp1[tp + 128], f13 = xp1[tp + 192];

            // h broadcast, both batches: 2 x 8 b128 reads, conflict-free.
            // Queue behind the previous step's ds_write_b16s (same-wave DS
            // in-order) — no waitcnt between writes and reads.
            uint4 hb0[8], hb1[8];
            const uint4* hp0 = (const uint4*)hs[0];
            const uint4* hp1 = (const uint4*)hs[1];
            #pragma unroll
            for (int q = 0; q < 8; ++q) { hb0[q] = hp0[q]; hb1[q] = hp1[q]; }
            const unsigned* hu0 = (const unsigned*)hb0;
            const unsigned* hu1 = (const unsigned*)hb1;

            // 2 partial accumulators per gate per batch: 16 chains of 16.
            float ai00 = p0c0, af00 = p0c1, ag00 = p0c2, ao00 = p0c3;
            float ai01 = 0.0f, af01 = 0.0f, ag01 = 0.0f, ao01 = 0.0f;
            float ai10 = p1c0, af10 = p1c1, ag10 = p1c2, ao10 = p1c3;
            float ai11 = 0.0f, af11 = 0.0f, ag11 = 0.0f, ao11 = 0.0f;
            #pragma unroll
            for (int q = 0; q < 32; q += 2) {
                half2_t x00 = H2(hu0[q]), x01 = H2(hu0[q + 1]);
                half2_t x10 = H2(hu1[q]), x11 = H2(hu1[q + 1]);
                ai00 = __builtin_amdgcn_fdot2(H2(wi[q]),     x00, ai00, false);
                ai10 = __builtin_amdgcn_fdot2(H2(wi[q]),     x10, ai10, false);
                af00 = __builtin_amdgcn_fdot2(H2(wf[q]),     x00, af00, false);
                af10 = __builtin_amdgcn_fdot2(H2(wf[q]),     x10, af10, false);
                ag00 = __builtin_amdgcn_fdot2(H2(wg[q]),     x00, ag00, false);
                ag10 = __builtin_amdgcn_fdot2(H2(wg[q]),     x10, ag10, false);
                ao00 = __builtin_amdgcn_fdot2(H2(wo[q]),     x00, ao00, false);
                ao10 = __builtin_amdgcn_fdot2(H2(wo[q]),     x10, ao10, false);
                ai01 = __builtin_amdgcn_fdot2(H2(wi[q + 1]), x01, ai01, false);
                ai11 = __builtin_amdgcn_fdot2(H2(wi[q + 1]), x11, ai11, false);
                af01 = __builtin_amdgcn_fdot2(H2(wf[q + 1]), x01, af01, false);
                af11 = __builtin_amdgcn_fdot2(H2(wf[q + 1]), x11, af11, false);
                ag01 = __builtin_amdgcn_fdot2(H2(wg[q + 1]), x01, ag01, false);
                ag11 = __builtin_amdgcn_fdot2(H2(wg[q + 1]), x11, ag11, false);
                ao01 = __builtin_amdgcn_fdot2(H2(wo[q + 1]), x01, ao01, false);
                ao11 = __builtin_amdgcn_fdot2(H2(wo[q + 1]), x11, ao11, false);
            }
            const float ai_0 = ai00 + ai01, af_0 = af00 + af01;
            const float ag_0 = ag00 + ag01, ao_0 = ao00 + ao01;
            const float ai_1 = ai10 + ai11, af_1 = af10 + af11;
            const float ag_1 = ag10 + ag11, ao_1 = ao10 + ao11;

            // Activation chains, interleaved (independent across batches)
            const float I0 = __builtin_amdgcn_rcpf(1.0f + EXP2N(-LOG2E * ai_0));
            const float I1 = __builtin_amdgcn_rcpf(1.0f + EXP2N(-LOG2E * ai_1));
            const float F0 = __builtin_amdgcn_rcpf(1.0f + EXP2N(-LOG2E * af_0));
            const float F1 = __builtin_amdgcn_rcpf(1.0f + EXP2N(-LOG2E * af_1));
            const float O0 = __builtin_amdgcn_rcpf(1.0f + EXP2N(-LOG2E * ao_0));
            const float O1 = __builtin_amdgcn_rcpf(1.0f + EXP2N(-LOG2E * ao_1));
            const float rg0 = __builtin_amdgcn_rcpf(1.0f + EXP2N((2.0f * LOG2E) * ag_0));
            const float rg1 = __builtin_amdgcn_rcpf(1.0f + EXP2N((2.0f * LOG2E) * ag_1));
            const float IG0 = __builtin_fmaf(-(I0 + I0), rg0, I0);
            const float IG1 = __builtin_fmaf(-(I1 + I1), rg1, I1);
            c0 = __builtin_fmaf(F0, c0, IG0);
            c1 = __builtin_fmaf(F1, c1, IG1);
            const float rc0 = __builtin_amdgcn_rcpf(1.0f + EXP2N((2.0f * LOG2E) * c0));
            const float rc1 = __builtin_amdgcn_rcpf(1.0f + EXP2N((2.0f * LOG2E) * c1));
            h0 = __builtin_fmaf(-(O0 + O0), rc0, O0);
            h1 = __builtin_fmaf(-(O1 + O1), rc1, O1);

            hs[0][j] = (_Float16)h0;   // ds_write_b16; next iter's reads queue after
            hs[1][j] = (_Float16)h1;
            (&hacc0.x)[k] = h0;        // static index (unrolled)
            (&hacc1.x)[k] = h1;

            p0c0 = p0n0; p0c1 = p0n1; p0c2 = p0n2; p0c3 = p0n3;
            p0n0 = f00;  p0n1 = f01;  p0n2 = f02;  p0n3 = f03;
            p1c0 = p1n0; p1c1 = p1n1; p1c2 = p1n2; p1c3 = p1n3;
            p1n0 = f10;  p1n1 = f11;  p1n2 = f12;  p1n3 = f13;
        }
        hq40[tq * 64 + j] = hacc0;     // 16B/lane, once per 4 steps, per batch
        hq41[tq * 64 + j] = hacc1;
    }

    dout[B_ * T_ * 4 + b0 * 64 + j]           = h0;   // hT
    dout[B_ * T_ * 4 + B_ * 64 + b0 * 64 + j] = c0;   // cT
    dout[B_ * T_ * 4 + b1 * 64 + j]           = h1;
    dout[B_ * T_ * 4 + B_ * 64 + b1 * 64 + j] = c1;
}

// -------------------------------------------------------------------------
// Kernel 3: head — adapted to the tq-grouped hout layout (B,T/4,64,4).
// -------------------------------------------------------------------------
__global__ __launch_bounds__(256) void head_kernel(
    const float* __restrict__ hout, const float* __restrict__ hw,
    const float* __restrict__ hb, float* __restrict__ out)
{
    const int blk = blockIdx.x;
    const int tid = threadIdx.x;

    __shared__ __align__(16) float hsh[64 * 68];   // [t_local][unit], row stride 68
    __shared__ __align__(16) float wsh[256];
    __shared__ float bsh[4];

    const float4* s4 = (const float4*)(hout + (size_t)blk * 64 * 64);
    for (int q = tid; q < 1024; q += 256) {
        int tqL = q >> 6;             // local tq group 0..15
        int j   = q & 63;             // unit
        float4 v = s4[q];             // h[j] for t = tqL*4 .. tqL*4+3
        #pragma unroll
        for (int k = 0; k < 4; ++k)
            hsh[(tqL * 4 + k) * 68 + j] = (&v.x)[k];   // consecutive banks per lane
    }
    if (tid < 64) ((float4*)wsh)[tid] = ((const float4*)hw)[tid];
    if (tid < 4)  bsh[tid] = hb[tid];
    __syncthreads();

    const int r = tid >> 2, m = tid & 3;
    const float4* hv = (const float4*)(hsh + r * 68);
    const float4* wv = (const float4*)(wsh + m * 64);
    float acc = bsh[m];
    #pragma unroll
    for (int q = 0; q < 16; ++q) {
        float4 a = hv[q], w = wv[q];
        acc += a.x * w.x + a.y * w.y + a.z * w.z + a.w * w.w;
    }
    out[(size_t)blk * 256 + tid] = sigmoidf_(acc);
}

extern "C" void kernel_launch(void* const* d_in, const int* in_sizes, int n_in,
                              void* d_out, int out_size, void* d_ws, size_t ws_size,
                              hipStream_t stream) {
    const float* pressure = (const float*)d_in[0];
    const float* torque   = (const float*)d_in[1];
    const float* frag     = (const float*)d_in[2];
    const float* pw1 = (const float*)d_in[3];
    const float* pb1 = (const float*)d_in[4];
    const float* pw2 = (const float*)d_in[5];
    const float* pb2 = (const float*)d_in[6];
    const float* tw1 = (const float*)d_in[7];
    const float* tb1 = (const float*)d_in[8];
    const float* tw2 = (const float*)d_in[9];
    const float* tb2 = (const float*)d_in[10];
    const float* fw  = (const float*)d_in[11];
    const float* fb  = (const float*)d_in[12];
    const float* prw = (const float*)d_in[13];
    const float* prb = (const float*)d_in[14];
    const float* Wih = (const float*)d_in[15];
    const float* Whh = (const float*)d_in[16];
    const float* bih = (const float*)d_in[17];
    const float* bhh = (const float*)d_in[18];
    const float* hw  = (const float*)d_in[19];
    const float* hb  = (const float*)d_in[20];

    float* out = (float*)d_out;

    // workspace: xg (B*T*256 f32 = 16 MB, gate-blocked) | hout (4 MB, tq-grouped)
    float* xg   = (float*)d_ws;
    float* hout = xg + (size_t)B_ * T_ * 256;

    // Packed weights aliased into the hout region: consumed by encoder_kernel,
    // dead before lstm_kernel starts overwriting hout (stream-ordered).
    unsigned* w1pT = (unsigned*)hout;
    unsigned* w2g  = w1pT + W1PT_N;
    float*   prwT4 = (float*)(w2g + W2G_N);
    float*   wihT4 = prwT4 + PRWT_N;
    float*   bsumP = wihT4 + WIHT_N;

    prep_kernel<<<(PREP_TOTAL + 255) / 256, 256, 0, stream>>>(
        pw1, tw1, pw2, tw2, prw, Wih, bih, bhh,
        w1pT, w2g, prwT4, wihT4, bsumP);

    encoder_kernel<<<B_ * T_ / 4, 256, 0, stream>>>(
        pressure, torque, frag,
        pb1, tb1, pb2, tb2, fw, fb, prb,
        w1pT, w2g, prwT4, wihT4, bsumP, xg);

    lstm_kernel<<<B_ / 2, 64, 0, stream>>>(xg, Whh, hout, out);

    head_kernel<<<B_ * T_ / 64, 256, 0, stream>>>(hout, hw, hb, out);
}

// Round 10
// 195.978 us; speedup vs baseline: 1.3798x; 1.3798x over previous
//
#include <hip/hip_runtime.h>
#include <math.h>

// Problem constants
#define B_   64
#define T_   256
#define W_   20
#define NP_  6
#define NT_  12
#define CC_  32      // CONV_CH
#define FD_  8       // FRAG_DIM
#define PR_  64      // PROJ

#define LOG2E  1.4426950408889634f

typedef float v2f __attribute__((ext_vector_type(2)));
typedef _Float16 half2_t __attribute__((ext_vector_type(2)));

// Pin a single 32-bit value into a VGPR (opaque def; blocks remat/spill-sink).
#define PINU(x) asm volatile("" : "+v"(x))
// Wave-local LDS ordering: drain LDS ops only; no vmcnt, no barrier.
#define WAVE_SYNC() asm volatile("s_waitcnt lgkmcnt(0)" ::: "memory")

#define H2(u) __builtin_bit_cast(half2_t, (u))
// Native base-2 exp: exactly v_exp_f32. R3 POST-MORTEM: libm exp2f() goes
// through the OCML correctly-rounded path (multi-inst fixup) without
// fast-math -> +30us on the 256-step serial chain. Never use libm exp/exp2
// on the LSTM critical path.
#define EXP2N(x) __builtin_amdgcn_exp2f(x)

// ============================ SESSION LEDGER =============================
// Best verified build: THIS config @ 196.0/196.1us (encoder ~78, lstm 106,
// head ~8, prep ~4). Twice reproduced, spill-clean.
// Falsified levers (do not retry):
//  - encoder (256,5) or >=48 extra pinned VGPRs: scratch spill. Spill signal
//    is FETCH/WRITE ballooning, NOT VGPR_Count (can still read 64).
//  - encoder barrier removal via per-wave redundant w2p staging: +33us
//    (staging cost > wave-coupling cost; coupling hypothesis falsified).
//  - lstm chain restructuring (acc splits, clamp/fma folds): per-step
//    ~1000cy invariant (~106us).
//  - lstm 2-wave K-split: +9us (barrier drains vmcnt -> kills x-prefetch;
//    exchange ~210cy > 128cy issue saving).
//  - lstm 2-batch-per-wave interleave: lstm 106->181us. Per-step cost is
//    ADDITIVE in work (1000->1700cy for 2x) => the step is serialized
//    wave-level pipe occupancy (in-order LDS + trans + VALU chains), NOT
//    overlappable latency. No intra-wave TLP exists; inter-wave TLP
//    impossible (serial recurrence, 1 wave/CU already).
// CONCLUSION: both hot kernels are latency/pipe-bound far below HBM (2-3%)
// and compute rooflines; all identified structural levers experimentally
// exhausted at ~196us.
// =========================================================================

__device__ __forceinline__ unsigned packh2(float a, float b) {
    union { _Float16 h[2]; unsigned u; } cv;
    cv.h[0] = (_Float16)a; cv.h[1] = (_Float16)b;
    return cv.u;
}

// Fast activations: v_rcp_f32 instead of IEEE division.
__device__ __forceinline__ float sigmoidf_(float x) {
    return __builtin_amdgcn_rcpf(1.0f + EXP2N(-LOG2E * x));  // exact at +-inf
}

// -------------------------------------------------------------------------
// Packed-weight sections (32-bit words), aliased into the hout workspace
// region: they are consumed by encoder_kernel and dead before lstm_kernel
// starts writing hout (stream order guarantees no overlap in time).
// -------------------------------------------------------------------------
#define W1PT_N  (18 * 64)          // conv1 wts, f16-pair, [m*3+k][lane]
#define W2G_N   (64 * 48)          // conv2 wts, f16-pair, [row][m*3+k]
#define PRWT_N  (18 * 64 * 4)      // proj wts, f32, float4 idx [kq][lane]
#define WIHT_N  (16 * 4 * 64 * 4)  // Wih, f32, float4 idx [kq][gate][lane]
#define BSUM_N  256                // bih + bhh
#define PREP_TOTAL (W1PT_N + W2G_N + PRWT_N + WIHT_N + BSUM_N)  // 25472

// -------------------------------------------------------------------------
// Kernel 0: weight repack (coalesced encoder weight loads; R11 win).
// -------------------------------------------------------------------------
__global__ void prep_kernel(
    const float* __restrict__ pw1, const float* __restrict__ tw1,
    const float* __restrict__ pw2, const float* __restrict__ tw2,
    const float* __restrict__ prw, const float* __restrict__ Wih,
    const float* __restrict__ bih, const float* __restrict__ bhh,
    unsigned* __restrict__ w1pT, unsigned* __restrict__ w2g,
    float* __restrict__ prwT4, float* __restrict__ wihT4,
    float* __restrict__ bsum)
{
    int id = blockIdx.x * 256 + threadIdx.x;
    if (id < W1PT_N) {
        // w1pT[m3*64 + lane] = packed conv1 pair (zero-padded for pressure m>=3)
        int lane = id & 63, m3 = id >> 6;
        int s = lane >> 5, o = lane & 31;
        int m = m3 / 3, k = m3 - 3 * m;
        unsigned v;
        if (s == 0)
            v = (m < 3) ? packh2(pw1[o * 18 + (2 * m) * 3 + k],
                                 pw1[o * 18 + (2 * m + 1) * 3 + k]) : 0u;
        else
            v = packh2(tw1[o * 36 + (2 * m) * 3 + k],
                       tw1[o * 36 + (2 * m + 1) * 3 + k]);
        w1pT[id] = v;
        return;
    }
    id -= W1PT_N;
    if (id < W2G_N) {
        // w2g[r*48 + c]: packed conv2 pair for out-row r (p:0-31, t:32-63)
        int r = id / 48, c = id - 48 * r;
        int s = r >> 5, o = r & 31;
        int m = c / 3, k = c - 3 * m;
        const float* src = s ? tw2 : pw2;
        w2g[id] = packh2(src[o * 96 + (2 * m) * 3 + k],
                         src[o * 96 + (2 * m + 1) * 3 + k]);
        return;
    }
    id -= W2G_N;
    if (id < PRWT_N) {
        // float4 index (kq*64 + lane), element j: prw[lane][kq*4+j]
        int j = id & 3, t = id >> 2;
        int lane = t & 63, kq = t >> 6;
        prwT4[id] = prw[lane * 72 + kq * 4 + j];
        return;
    }
    id -= PRWT_N;
    if (id < WIHT_N) {
        // float4 index ((kq*4+gi)*64 + lane), element j: Wih[gi*64+lane][kq*4+j]
        int j = id & 3, t = id >> 2;
        int lane = t & 63, gg = t >> 6;
        int gi = gg & 3, kq = gg >> 2;
        wihT4[id] = Wih[(gi * 64 + lane) * 64 + kq * 4 + j];
        return;
    }
    id -= WIHT_N;
    if (id < BSUM_N) bsum[id] = bih[id] + bhh[id];
}

// -------------------------------------------------------------------------
// Kernel 1: encoders + projection + LSTM input-gate precompute.
// R4-EXACT structure (verified ~78us, FETCH 12MB, WRITE 16MB, VGPR 64):
// cooperative w2p staging + the ONE __syncthreads + (256,4). See ledger.
// -------------------------------------------------------------------------
__global__ __launch_bounds__(256, 4) void encoder_kernel(
    const float* __restrict__ pressure, const float* __restrict__ torque,
    const float* __restrict__ frag,
    const float* __restrict__ pb1, const float* __restrict__ tb1,
    const float* __restrict__ pb2, const float* __restrict__ tb2,
    const float* __restrict__ fw,  const float* __restrict__ fb,
    const float* __restrict__ prb,
    const unsigned* __restrict__ w1pT, const unsigned* __restrict__ w2g,
    const float* __restrict__ prwT4, const float* __restrict__ wihT4,
    const float* __restrict__ bsum,
    float* __restrict__ xg)             // (B,T,4gates,64units) gate-blocked
{
    const int tid  = threadIdx.x;       // 0..255
    const int wv   = tid >> 6;          // wave 0..3
    const int lane = tid & 63;
    const int bt   = blockIdx.x * 4 + wv;   // window id
    const int b    = bt >> 8;
    const int  o   = lane & 31;
    const bool isp = lane < 32;
    const int  s   = isp ? 0 : 1;       // stream: 0=pressure, 1=torque

    __shared__ unsigned w2p[64 * 49];                    // 12544 B packed conv2 wts
    __shared__ __align__(16) unsigned xwp[4][2][120];    //  3840 B [wave][stream][pair*20+pos]
    __shared__ __align__(16) unsigned h1p[4][2][320];    // 10240 B
    __shared__ __align__(16) float catb4[4][72];
    __shared__ __align__(16) float featsh4[4][64];

    float* catb   = catb4[wv];
    float* featsh = featsh4[wv];

    // ---- stage conv2 weights once per block (coalesced b32 from w2g) ----
    for (int idx = tid; idx < 64 * 48; idx += 256) {
        int r = idx / 48, c = idx - r * 48;
        w2p[r * 49 + c] = w2g[idx];
    }

    // ---- zero + stage own window as packed f16 pairs (transposed) ----
    {
        unsigned* xz = &xwp[wv][0][0];
        #pragma unroll
        for (int idx = lane; idx < 240; idx += 64) xz[idx] = 0;   // pads pressure rows 3..5
    }
    const float* pin = pressure + (size_t)bt * (W_ * NP_);
    for (int idx = lane; idx < W_ * NP_; idx += 64) {
        int w = idx / NP_, i = idx - w * NP_;
        ((_Float16*)&xwp[wv][0][(i >> 1) * 20 + w])[i & 1] = (_Float16)pin[idx];
    }
    const float* tin = torque + (size_t)bt * (W_ * NT_);
    for (int idx = lane; idx < W_ * NT_; idx += 64) {
        int w = idx / NT_, i = idx - w * NT_;
        ((_Float16*)&xwp[wv][1][(i >> 1) * 20 + w])[i & 1] = (_Float16)tin[idx];
    }
    if (lane < FD_) catb[64 + lane] = fmaxf(frag[b] * fw[lane] + fb[lane], 0.0f);

    // ---- conv1 weights: one coalesced b32 load per pair slot ----
    unsigned w1p[18];
    #pragma unroll
    for (int m3 = 0; m3 < 18; ++m3) w1p[m3] = w1pT[m3 * 64 + lane];

    const float bz1 = isp ? pb1[o] : tb1[o];
    const float bz2 = isp ? pb2[o] : tb2[o];
    WAVE_SYNC();    // xwp visible within the wave

    // ---- conv1: 6 pair-rows x 3 taps x 18 pos, dot2 f16 -> f32 acc ----
    {
        const unsigned* xr = &xwp[wv][s][0];
        float acc[18];
        #pragma unroll
        for (int l = 0; l < 18; ++l) acc[l] = bz1;
        #pragma unroll
        for (int m = 0; m < 6; ++m) {
            uint4 r4[5];
            const uint4* rp = (const uint4*)(xr + m * 20);
            #pragma unroll
            for (int q = 0; q < 5; ++q) r4[q] = rp[q];        // broadcast b128
            const unsigned* rw = (const unsigned*)r4;
            const half2_t wk0 = H2(w1p[m * 3]), wk1 = H2(w1p[m * 3 + 1]), wk2 = H2(w1p[m * 3 + 2]);
            #pragma unroll
            for (int l = 0; l < 18; ++l) {
                float a = acc[l];
                a = __builtin_amdgcn_fdot2(wk0, H2(rw[l]),     a, false);
                a = __builtin_amdgcn_fdot2(wk1, H2(rw[l + 1]), a, false);
                a = __builtin_amdgcn_fdot2(wk2, H2(rw[l + 2]), a, false);
                acc[l] = a;
            }
        }
        #pragma unroll
        for (int l = 0; l < 18; ++l)
            ((_Float16*)&h1p[wv][s][(o >> 1) * 20 + l])[o & 1] = (_Float16)fmaxf(acc[l], 0.0f);
    }
    __syncthreads();   // the ONE real barrier: w2p (cross-wave) + h1p ready

    // ---- conv2: 16 pair-rows x 3 taps x 16 pos, weights from LDS ----
    {
        const unsigned* hr   = &h1p[wv][s][0];
        const unsigned* wrow = w2p + lane * 49;   // row stride 49: conflict-free
        float sacc[16];
        #pragma unroll
        for (int l = 0; l < 16; ++l) sacc[l] = bz2;
        #pragma unroll 4
        for (int m = 0; m < 16; ++m) {
            uint4 r4[5];
            const uint4* rp = (const uint4*)(hr + m * 20);
            #pragma unroll
            for (int q = 0; q < 5; ++q) r4[q] = rp[q];        // broadcast b128
            const unsigned* rw = (const unsigned*)r4;
            const half2_t wk0 = H2(wrow[m * 3]), wk1 = H2(wrow[m * 3 + 1]), wk2 = H2(wrow[m * 3 + 2]);
            #pragma unroll
            for (int l = 0; l < 16; ++l) {
                float a = sacc[l];
                a = __builtin_amdgcn_fdot2(wk0, H2(rw[l]),     a, false);
                a = __builtin_amdgcn_fdot2(wk1, H2(rw[l + 1]), a, false);
                a = __builtin_amdgcn_fdot2(wk2, H2(rw[l + 2]), a, false);
                sacc[l] = a;
            }
        }
        float m2 = 0.0f;
        #pragma unroll
        for (int l = 0; l < 16; ++l) m2 += fmaxf(sacc[l], 0.0f);
        catb[lane] = m2 * 0.0625f;               // pf -> [0..31], tf -> [32..63]
    }
    WAVE_SYNC();    // catb visible within the wave

    // ---- projection 72 -> 64, relu (f32, coalesced lane-interleaved wts) ----
    {
        float acc = prb[lane];
        const float4* w4 = (const float4*)prwT4;   // [q*64 + lane]
        const float4* c4 = (const float4*)catb;
        #pragma unroll
        for (int q = 0; q < 18; ++q) {
            float4 w = w4[q * 64 + lane];
            float4 cv = c4[q];
            acc += w.x * cv.x + w.y * cv.y + w.z * cv.z + w.w * cv.w;
        }
        featsh[lane] = fmaxf(acc, 0.0f);
    }
    WAVE_SYNC();    // featsh visible within the wave

    // ---- xg = feat @ Wih.T + bsum ; coalesced wts + coalesced stores ----
    {
        float4 fr[16];
        const float4* f4 = (const float4*)featsh;
        #pragma unroll
        for (int q = 0; q < 16; ++q) fr[q] = f4[q];
        float* xgrow = xg + (size_t)bt * 256;
        const float4* w44 = (const float4*)wihT4;  // [(q*4+gi)*64 + lane]
        #pragma unroll
        for (int gi = 0; gi < 4; ++gi) {
            float acc = bsum[gi * 64 + lane];
            #pragma unroll
            for (int q = 0; q < 16; ++q) {
                float4 w = w44[(q * 4 + gi) * 64 + lane];
                acc += w.x * fr[q].x + w.y * fr[q].y + w.z * fr[q].z + w.w * fr[q].w;
            }
            xgrow[gi * 64 + lane] = acc;         // 256B contiguous per store inst
        }
    }
}

// -------------------------------------------------------------------------
// Kernel 2: LSTM — single wave per element, f16 weights + v_dot2_f32_f16.
// R4-exact (106us, best measured; see ledger for the falsified variants).
// Unclamped prefetch: overflow reads land in the packed-weight/hout region
// (allocated, values never consumed).
// -------------------------------------------------------------------------
__global__ __launch_bounds__(64, 1) void lstm_kernel(
    const float* __restrict__ xg,     // (B,T,4,64), bias already included
    const float* __restrict__ Whh,    // (256,64)
    float* __restrict__ hout,         // (B, T/4, 64units, 4t)
    float* __restrict__ dout)         // full output buffer
{
    const int b = blockIdx.x;
    const int j = threadIdx.x;        // hidden unit index

    __shared__ __align__(16) _Float16 hs[64];    // h state in f16 (128 B)

    // 4 Whh rows for unit j (i,f,g,o) as f16 pairs: 4 x 32 uints, pinned
    unsigned wi[32], wf[32], wg[32], wo[32];
    {
        const v2f* ri = (const v2f*)(Whh + (size_t)(j)       * 64);
        const v2f* rf = (const v2f*)(Whh + (size_t)(64  + j) * 64);
        const v2f* rg = (const v2f*)(Whh + (size_t)(128 + j) * 64);
        const v2f* ro = (const v2f*)(Whh + (size_t)(192 + j) * 64);
        #pragma unroll
        for (int q = 0; q < 32; ++q) {
            v2f w;
            w = ri[q]; wi[q] = packh2(w.x, w.y);
            w = rf[q]; wf[q] = packh2(w.x, w.y);
            w = rg[q]; wg[q] = packh2(w.x, w.y);
            w = ro[q]; wo[q] = packh2(w.x, w.y);
        }
        #pragma unroll
        for (int q = 0; q < 32; ++q) { PINU(wi[q]); PINU(wf[q]); PINU(wg[q]); PINU(wo[q]); }
    }

    const float* xp = xg + (size_t)b * T_ * 256 + j;
    float4* hq4 = (float4*)(hout + (size_t)b * T_ * 64);   // + tq*64 + j (float4 units)

    float c = 0.0f;
    float h = 0.0f;
    hs[j] = (_Float16)0.0f;
    WAVE_SYNC();    // once, before the loop

    // 2-deep prefetch of the 4 per-step gate scalars
    float xc0 = xp[0],   xc1 = xp[64],  xc2 = xp[128], xc3 = xp[192];
    float xn0 = xp[256], xn1 = xp[320], xn2 = xp[384], xn3 = xp[448];

    for (int tq = 0; tq < T_ / 4; ++tq) {
        float4 hacc;
        #pragma unroll
        for (int k = 0; k < 4; ++k) {
            const int t = tq * 4 + k;
            const int tp = (t + 2) * 256;   // unclamped: overflow lands in hout
                                            // region (allocated, never consumed)
            float xf0 = xp[tp], xf1 = xp[tp + 64], xf2 = xp[tp + 128], xf3 = xp[tp + 192];

            // h broadcast: 64 halfs = 128 B = 8 x b128 reads, conflict-free.
            // These queue behind the previous step's ds_write_b16 (same-wave
            // DS in-order) — no waitcnt between write and reads.
            uint4 hb[8];
            const uint4* hp = (const uint4*)hs;
            #pragma unroll
            for (int q = 0; q < 8; ++q) hb[q] = hp[q];
            const unsigned* hu = (const unsigned*)hb;

            // 2 partial accumulators per gate: chains of 16, 8-way ILP
            float ai0 = xc0, af0 = xc1, ag0 = xc2, ao0 = xc3;
            float ai1 = 0.0f, af1 = 0.0f, ag1 = 0.0f, ao1 = 0.0f;
            #pragma unroll
            for (int q = 0; q < 32; q += 2) {
                half2_t h0 = H2(hu[q]), h1 = H2(hu[q + 1]);
                ai0 = __builtin_amdgcn_fdot2(H2(wi[q]),     h0, ai0, false);
                af0 = __builtin_amdgcn_fdot2(H2(wf[q]),     h0, af0, false);
                ag0 = __builtin_amdgcn_fdot2(H2(wg[q]),     h0, ag0, false);
                ao0 = __builtin_amdgcn_fdot2(H2(wo[q]),     h0, ao0, false);
                ai1 = __builtin_amdgcn_fdot2(H2(wi[q + 1]), h1, ai1, false);
                af1 = __builtin_amdgcn_fdot2(H2(wf[q + 1]), h1, af1, false);
                ag1 = __builtin_amdgcn_fdot2(H2(wg[q + 1]), h1, ag1, false);
                ao1 = __builtin_amdgcn_fdot2(H2(wo[q + 1]), h1, ao1, false);
            }
            const float ai = ai0 + ai1, af = af0 + af1;
            const float ag = ag0 + ag1, ao = ao0 + ao1;

            // I,F,O sigmoids (off the c-critical-path, ILP with rg chain)
            const float I = __builtin_amdgcn_rcpf(1.0f + EXP2N(-LOG2E * ai));
            const float F = __builtin_amdgcn_rcpf(1.0f + EXP2N(-LOG2E * af));
            const float O = __builtin_amdgcn_rcpf(1.0f + EXP2N(-LOG2E * ao));
            // G = tanh(ag) = 1 - 2*rg, rg = rcp(e^{2ag}+1); fold: I*G = I - 2I*rg
            const float rgv = __builtin_amdgcn_rcpf(1.0f + EXP2N((2.0f * LOG2E) * ag));
            const float IG  = __builtin_fmaf(-(I + I), rgv, I);
            c = __builtin_fmaf(F, c, IG);
            // h = O*tanh(c) = O - 2O*rc
            const float rcv = __builtin_amdgcn_rcpf(1.0f + EXP2N((2.0f * LOG2E) * c));
            h = __builtin_fmaf(-(O + O), rcv, O);

            hs[j] = (_Float16)h;      // ds_write_b16; next iter's reads queue after it
            (&hacc.x)[k] = h;         // static index (unrolled)

            xc0 = xn0; xc1 = xn1; xc2 = xn2; xc3 = xn3;
            xn0 = xf0; xn1 = xf1; xn2 = xf2; xn3 = xf3;
        }
        hq4[tq * 64 + j] = hacc;      // 16B/lane, 1KB/wave, once per 4 steps
    }

    dout[B_ * T_ * 4 + b * 64 + j]           = h;   // hT
    dout[B_ * T_ * 4 + B_ * 64 + b * 64 + j] = c;   // cT
}

// -------------------------------------------------------------------------
// Kernel 3: head — adapted to the tq-grouped hout layout (B,T/4,64,4).
// -------------------------------------------------------------------------
__global__ __launch_bounds__(256) void head_kernel(
    const float* __restrict__ hout, const float* __restrict__ hw,
    const float* __restrict__ hb, float* __restrict__ out)
{
    const int blk = blockIdx.x;
    const int tid = threadIdx.x;

    __shared__ __align__(16) float hsh[64 * 68];   // [t_local][unit], row stride 68
    __shared__ __align__(16) float wsh[256];
    __shared__ float bsh[4];

    const float4* s4 = (const float4*)(hout + (size_t)blk * 64 * 64);
    for (int q = tid; q < 1024; q += 256) {
        int tqL = q >> 6;             // local tq group 0..15
        int j   = q & 63;             // unit
        float4 v = s4[q];             // h[j] for t = tqL*4 .. tqL*4+3
        #pragma unroll
        for (int k = 0; k < 4; ++k)
            hsh[(tqL * 4 + k) * 68 + j] = (&v.x)[k];   // consecutive banks per lane
    }
    if (tid < 64) ((float4*)wsh)[tid] = ((const float4*)hw)[tid];
    if (tid < 4)  bsh[tid] = hb[tid];
    __syncthreads();

    const int r = tid >> 2, m = tid & 3;
    const float4* hv = (const float4*)(hsh + r * 68);
    const float4* wv = (const float4*)(wsh + m * 64);
    float acc = bsh[m];
    #pragma unroll
    for (int q = 0; q < 16; ++q) {
        float4 a = hv[q], w = wv[q];
        acc += a.x * w.x + a.y * w.y + a.z * w.z + a.w * w.w;
    }
    out[(size_t)blk * 256 + tid] = sigmoidf_(acc);
}

extern "C" void kernel_launch(void* const* d_in, const int* in_sizes, int n_in,
                              void* d_out, int out_size, void* d_ws, size_t ws_size,
                              hipStream_t stream) {
    const float* pressure = (const float*)d_in[0];
    const float* torque   = (const float*)d_in[1];
    const float* frag     = (const float*)d_in[2];
    const float* pw1 = (const float*)d_in[3];
    const float* pb1 = (const float*)d_in[4];
    const float* pw2 = (const float*)d_in[5];
    const float* pb2 = (const float*)d_in[6];
    const float* tw1 = (const float*)d_in[7];
    const float* tb1 = (const float*)d_in[8];
    const float* tw2 = (const float*)d_in[9];
    const float* tb2 = (const float*)d_in[10];
    const float* fw  = (const float*)d_in[11];
    const float* fb  = (const float*)d_in[12];
    const float* prw = (const float*)d_in[13];
    const float* prb = (const float*)d_in[14];
    const float* Wih = (const float*)d_in[15];
    const float* Whh = (const float*)d_in[16];
    const float* bih = (const float*)d_in[17];
    const float* bhh = (const float*)d_in[18];
    const float* hw  = (const float*)d_in[19];
    const float* hb  = (const float*)d_in[20];

    float* out = (float*)d_out;

    // workspace: xg (B*T*256 f32 = 16 MB, gate-blocked) | hout (4 MB, tq-grouped)
    float* xg   = (float*)d_ws;
    float* hout = xg + (size_t)B_ * T_ * 256;

    // Packed weights aliased into the hout region: consumed by encoder_kernel,
    // dead before lstm_kernel starts overwriting hout (stream-ordered).
    unsigned* w1pT = (unsigned*)hout;
    unsigned* w2g  = w1pT + W1PT_N;
    float*   prwT4 = (float*)(w2g + W2G_N);
    float*   wihT4 = prwT4 + PRWT_N;
    float*   bsumP = wihT4 + WIHT_N;

    prep_kernel<<<(PREP_TOTAL + 255) / 256, 256, 0, stream>>>(
        pw1, tw1, pw2, tw2, prw, Wih, bih, bhh,
        w1pT, w2g, prwT4, wihT4, bsumP);

    encoder_kernel<<<B_ * T_ / 4, 256, 0, stream>>>(
        pressure, torque, frag,
        pb1, tb1, pb2, tb2, fw, fb, prb,
        w1pT, w2g, prwT4, wihT4, bsumP, xg);

    lstm_kernel<<<B_, 64, 0, stream>>>(xg, Whh, hout, out);

    head_kernel<<<B_ * T_ / 64, 256, 0, stream>>>(hout, hw, hb, out);
}